// Round 1
// baseline (1499.118 us; speedup 1.0000x reference)
//
#include <hip/hip_runtime.h>
#include <math.h>

static const int NA = 20000;
static const int NE = 320000;
static const int F  = 128;
static const long NF = (long)NA * F;   // 2,560,000

// ---------------------------------------------------------------- geometry
// edata layout per edge (24 floats): [fc, ux, uy, uz, rbf0..rbf19] where
// rbf_k = sin((k+1)*pi*d/5)/d * fc   (fc folded in; bias term uses fc slot)
__global__ void geom_kernel(const float* __restrict__ xyz, const int* __restrict__ nbrs,
                            float* __restrict__ edata) {
    int e = blockIdx.x * 256 + threadIdx.x;
    if (e >= NE) return;
    int i = nbrs[2 * e], j = nbrs[2 * e + 1];
    float xi = xyz[3 * i], yi = xyz[3 * i + 1], zi = xyz[3 * i + 2];
    float xj = xyz[3 * j], yj = xyz[3 * j + 1], zj = xyz[3 * j + 2];
    float rx = xj - xi, ry = yj - yi, rz = zj - zi;
    float d2 = rx * rx + ry * ry + rz * rz + 1e-15f;
    float d = sqrtf(d2);
    float inv = 1.0f / d;
    float fc = (d < 5.0f) ? 0.5f * (cosf(d * (float)M_PI / 5.0f) + 1.0f) : 0.0f;
    float* ed = edata + (size_t)e * 24;
    ed[0] = fc; ed[1] = rx * inv; ed[2] = ry * inv; ed[3] = rz * inv;
    float x = d * (float)M_PI / 5.0f;
    float s1 = sinf(x), c1 = cosf(x);
    float skm1 = 0.f, sk = s1;
    float twoc = 2.f * c1;
    float scale = inv * fc;
    #pragma unroll
    for (int k = 0; k < 20; k++) {
        ed[4 + k] = sk * scale;
        float skp1 = twoc * sk - skm1;
        skm1 = sk; sk = skp1;
    }
}

// ---------------------------------------------------------------- CSR build
__global__ void hist_kernel(const int* __restrict__ nbrs, int* __restrict__ cnt) {
    int e = blockIdx.x * 256 + threadIdx.x;
    if (e < NE) atomicAdd(&cnt[nbrs[2 * e]], 1);
}

__global__ __launch_bounds__(1024) void scan_kernel(const int* __restrict__ cnt, int* __restrict__ offs) {
    __shared__ int sh[1024];
    int t = threadIdx.x;
    int carry = 0;
    for (int base = 0; base < NA; base += 1024) {
        int idx = base + t;
        int x = (idx < NA) ? cnt[idx] : 0;
        sh[t] = x;
        __syncthreads();
        for (int o = 1; o < 1024; o <<= 1) {
            int v = (t >= o) ? sh[t - o] : 0;
            __syncthreads();
            sh[t] += v;
            __syncthreads();
        }
        int incl = sh[t];
        if (idx < NA) offs[idx] = carry + incl - x;
        int total = sh[1023];
        __syncthreads();
        carry += total;
    }
    if (t == 0) offs[NA] = carry;
}

__global__ void fill_kernel(const int* __restrict__ nbrs, const int* __restrict__ offs,
                            int* __restrict__ cur, int* __restrict__ perm) {
    int e = blockIdx.x * 256 + threadIdx.x;
    if (e < NE) {
        int i = nbrs[2 * e];
        int p = atomicAdd(&cur[i], 1);
        perm[offs[i] + p] = e;
    }
}

// ---------------------------------------------------------------- embed
__global__ void embed_kernel(const int* __restrict__ z, const float* __restrict__ embed,
                             float* __restrict__ s) {
    int idx = blockIdx.x * 256 + threadIdx.x;
    if (idx >= NA * F) return;
    int n = idx >> 7, f = idx & 127;
    s[idx] = embed[z[n] * F + f];
}

// ---------------------------------------------------------------- GEMM (fp32)
// BM=128, BN=64, BK=64, 256 threads, 8x4 microtile. act: 0 none, 1 silu, 2 relu
__device__ __forceinline__ float epilogue_act(float x, int act) {
    if (act == 1) return x / (1.0f + expf(-x));
    if (act == 2) return fmaxf(x, 0.0f);
    return x;
}

__device__ __forceinline__ void gemm_body(float* smem,
                                          const float* __restrict__ A, const float* __restrict__ W,
                                          const float* __restrict__ bias, float* __restrict__ C,
                                          int K, int Cout, int act) {
    float (*As)[65] = (float(*)[65])smem;                 // 128 x 65
    float (*Ws)[64] = (float(*)[64])(smem + 128 * 65);    // 64 x 64
    int tid = threadIdx.x;
    int tx = tid & 15, ty = tid >> 4;
    int r0 = blockIdx.x * 128;
    int c0 = blockIdx.y * 64;
    float acc[8][4];
    #pragma unroll
    for (int a = 0; a < 8; a++)
        #pragma unroll
        for (int b = 0; b < 4; b++) acc[a][b] = 0.f;

    for (int k0 = 0; k0 < K; k0 += 64) {
        #pragma unroll
        for (int q = 0; q < 8; q++) {
            int row = ty + q * 16;
            int col = tx * 4;
            int gr = r0 + row;
            float4 va = make_float4(0.f, 0.f, 0.f, 0.f);
            if (gr < NA) va = *(const float4*)(A + (size_t)gr * K + k0 + col);
            As[row][col + 0] = va.x; As[row][col + 1] = va.y;
            As[row][col + 2] = va.z; As[row][col + 3] = va.w;
        }
        #pragma unroll
        for (int q = 0; q < 4; q++) {
            int row = ty + q * 16;
            int col = tx * 4;
            int gc = c0 + col;
            float4 vw = make_float4(0.f, 0.f, 0.f, 0.f);
            if (gc < Cout) vw = *(const float4*)(W + (size_t)(k0 + row) * Cout + gc);
            *(float4*)(&Ws[row][col]) = vw;
        }
        __syncthreads();
        #pragma unroll 8
        for (int kk = 0; kk < 64; ++kk) {
            float4 b = *(const float4*)(&Ws[kk][tx * 4]);
            #pragma unroll
            for (int ri = 0; ri < 8; ++ri) {
                float a = As[ty * 8 + ri][kk];
                acc[ri][0] += a * b.x; acc[ri][1] += a * b.y;
                acc[ri][2] += a * b.z; acc[ri][3] += a * b.w;
            }
        }
        __syncthreads();
    }
    int gc = c0 + tx * 4;
    if (gc < Cout) {
        float bb0 = 0.f, bb1 = 0.f, bb2 = 0.f, bb3 = 0.f;
        if (bias) { bb0 = bias[gc]; bb1 = bias[gc + 1]; bb2 = bias[gc + 2]; bb3 = bias[gc + 3]; }
        #pragma unroll
        for (int ri = 0; ri < 8; ri++) {
            int gr = r0 + ty * 8 + ri;
            if (gr < NA) {
                float4 o;
                o.x = epilogue_act(acc[ri][0] + bb0, act);
                o.y = epilogue_act(acc[ri][1] + bb1, act);
                o.z = epilogue_act(acc[ri][2] + bb2, act);
                o.w = epilogue_act(acc[ri][3] + bb3, act);
                *(float4*)(C + (size_t)gr * Cout + gc) = o;
            }
        }
    }
}

template<int ACT>
__global__ __launch_bounds__(256) void gemm_kernel(const float* __restrict__ A, const float* __restrict__ W,
                                                   const float* __restrict__ bias, float* __restrict__ C,
                                                   int K, int Cout) {
    __shared__ float smem[128 * 65 + 64 * 64];
    gemm_body(smem, A, W, bias, C, K, Cout, ACT);
}

// batched u_v / v_v: grid.z = 6 -> (mat = z/3 in {U,V}, d = z%3)
__global__ __launch_bounds__(256) void gemm_uvvv_kernel(const float* __restrict__ vB,
                                                        const float* __restrict__ U, const float* __restrict__ V,
                                                        float* __restrict__ uv, float* __restrict__ vv) {
    __shared__ float smem[128 * 65 + 64 * 64];
    int zz = blockIdx.z;
    int d = zz % 3;
    const float* A = vB + (size_t)d * NF;
    const float* W = (zz < 3) ? U : V;
    float* C = ((zz < 3) ? uv : vv) + (size_t)d * NF;
    gemm_body(smem, A, W, nullptr, C, 128, 128, 0);
}

// ---------------------------------------------------------------- message + aggregation
// one block (128 threads) per atom i; Wd columns live in registers; CSR edge list
__global__ __launch_bounds__(128) void msg_kernel(
    const float* __restrict__ phi, const float* __restrict__ edata,
    const int* __restrict__ nbrs, const int* __restrict__ offs, const int* __restrict__ perm,
    const float* __restrict__ Wd, const float* __restrict__ bd,
    const float* __restrict__ vin, float* __restrict__ vout, float* __restrict__ s) {
    int i = blockIdx.x;
    int f = threadIdx.x;
    float wd0[20], wd1[20], wd2[20];
    #pragma unroll
    for (int k = 0; k < 20; k++) {
        wd0[k] = Wd[k * 384 + f];
        wd1[k] = Wd[k * 384 + 128 + f];
        wd2[k] = Wd[k * 384 + 256 + f];
    }
    float b0 = bd[f], b1 = bd[128 + f], b2 = bd[256 + f];
    float accS = 0.f, aV0 = 0.f, aV1 = 0.f, aV2 = 0.f;
    int p0 = offs[i], p1 = offs[i + 1];
    for (int p = p0; p < p1; ++p) {
        int e = perm[p];
        int j = nbrs[2 * e + 1];
        const float4* ed = (const float4*)(edata + (size_t)e * 24);
        float4 q0 = ed[0], q1 = ed[1], q2 = ed[2], q3 = ed[3], q4 = ed[4], q5 = ed[5];
        float fc = q0.x, ux = q0.y, uy = q0.z, uz = q0.w;
        float rb[20];
        rb[0]=q1.x; rb[1]=q1.y; rb[2]=q1.z; rb[3]=q1.w;
        rb[4]=q2.x; rb[5]=q2.y; rb[6]=q2.z; rb[7]=q2.w;
        rb[8]=q3.x; rb[9]=q3.y; rb[10]=q3.z; rb[11]=q3.w;
        rb[12]=q4.x; rb[13]=q4.y; rb[14]=q4.z; rb[15]=q4.w;
        rb[16]=q5.x; rb[17]=q5.y; rb[18]=q5.z; rb[19]=q5.w;
        float w0 = b0 * fc, w1 = b1 * fc, w2 = b2 * fc;
        #pragma unroll
        for (int k = 0; k < 20; k++) {
            w0 += rb[k] * wd0[k];
            w1 += rb[k] * wd1[k];
            w2 += rb[k] * wd2[k];
        }
        const float* pj = phi + (size_t)j * 384;
        float i0 = pj[f] * w0, i1 = pj[128 + f] * w1, i2 = pj[256 + f] * w2;
        size_t jb = (size_t)j * F + f;
        accS += i1;
        aV0 += i2 * ux + i0 * vin[jb];
        aV1 += i2 * uy + i0 * vin[NF + jb];
        aV2 += i2 * uz + i0 * vin[2 * NF + jb];
    }
    size_t ib = (size_t)i * F + f;
    s[ib] += accS;
    vout[ib]          = vin[ib] + aV0;
    vout[NF + ib]     = vin[NF + ib] + aV1;
    vout[2 * NF + ib] = vin[2 * NF + ib] + aV2;
}

// ---------------------------------------------------------------- elementwise
__global__ void stack_kernel(const float* __restrict__ s, const float* __restrict__ vv,
                             float* __restrict__ stk) {
    int idx = blockIdx.x * 256 + threadIdx.x;
    if (idx >= NA * F) return;
    int n = idx >> 7, f = idx & 127;
    float a = vv[idx], b = vv[NF + idx], c = vv[2 * NF + idx];
    stk[(size_t)n * 256 + f] = s[idx];
    stk[(size_t)n * 256 + 128 + f] = sqrtf(a * a + b * b + c * c + 1e-15f);
}

__global__ void update_kernel(const float* __restrict__ split, const float* __restrict__ uv,
                              const float* __restrict__ vv, const float* __restrict__ vin,
                              float* __restrict__ vout, float* __restrict__ s) {
    int idx = blockIdx.x * 256 + threadIdx.x;
    if (idx >= NA * F) return;
    int n = idx >> 7, f = idx & 127;
    const float* sp = split + (size_t)n * 384;
    float avv = sp[f], asv = sp[128 + f], ass = sp[256 + f];
    float dot = 0.f;
    #pragma unroll
    for (int d = 0; d < 3; d++) {
        float u = uv[d * NF + idx];
        vout[d * NF + idx] = vin[d * NF + idx] + u * avv;
        dot += u * vv[d * NF + idx];
    }
    s[idx] += dot * asv + ass;
}

// ---------------------------------------------------------------- head
__global__ __launch_bounds__(256) void head_kernel(const float* __restrict__ h,
                                                   const float* __restrict__ Wo,
                                                   const float* __restrict__ bo,
                                                   float* __restrict__ out) {
    int n = blockIdx.x * 4 + (threadIdx.x >> 6);
    int lane = threadIdx.x & 63;
    if (n >= NA) return;
    float p = h[(size_t)n * 128 + lane] * Wo[lane] + h[(size_t)n * 128 + 64 + lane] * Wo[64 + lane];
    #pragma unroll
    for (int o = 32; o > 0; o >>= 1) p += __shfl_down(p, o);
    if (lane == 0) out[n] = p + bo[0];
}

// ---------------------------------------------------------------- host
extern "C" void kernel_launch(void* const* d_in, const int* in_sizes, int n_in,
                              void* d_out, int out_size, void* d_ws, size_t ws_size,
                              hipStream_t stream) {
    const float* xyz    = (const float*)d_in[0];
    const int*   z      = (const int*)d_in[1];
    const int*   nbrs   = (const int*)d_in[2];
    const float* embed  = (const float*)d_in[3];
    const float* msg_W1 = (const float*)d_in[4];
    const float* msg_b1 = (const float*)d_in[5];
    const float* msg_W2 = (const float*)d_in[6];
    const float* msg_b2 = (const float*)d_in[7];
    const float* msg_Wd = (const float*)d_in[8];
    const float* msg_bd = (const float*)d_in[9];
    const float* upd_U  = (const float*)d_in[10];
    const float* upd_V  = (const float*)d_in[11];
    const float* upd_Ws1= (const float*)d_in[12];
    const float* upd_bs1= (const float*)d_in[13];
    const float* upd_Ws2= (const float*)d_in[14];
    const float* upd_bs2= (const float*)d_in[15];
    const float* ro_W1  = (const float*)d_in[16];
    const float* ro_b1  = (const float*)d_in[17];
    const float* ro_W2  = (const float*)d_in[18];
    const float* ro_b2  = (const float*)d_in[19];
    const float* fc_W1  = (const float*)d_in[20];
    const float* fc_b1  = (const float*)d_in[21];
    const float* fc_W2  = (const float*)d_in[22];
    const float* fc_b2  = (const float*)d_in[23];
    const float* fc_Wo  = (const float*)d_in[24];
    const float* fc_bo  = (const float*)d_in[25];
    float* out = (float*)d_out;

    char* ws = (char*)d_ws;
    size_t off = 0;
    auto alloc = [&](size_t nbytes) -> char* {
        char* p = ws + off;
        off += (nbytes + 255) / 256 * 256;
        return p;
    };
    float* edata = (float*)alloc((size_t)NE * 24 * 4);
    float* s     = (float*)alloc((size_t)NA * F * 4);
    float* vA    = (float*)alloc((size_t)3 * NF * 4);
    float* vB    = (float*)alloc((size_t)3 * NF * 4);
    float* phi   = (float*)alloc((size_t)NA * 384 * 4);   // reused as split
    float* hid   = (float*)alloc((size_t)NA * F * 4);
    float* uv    = (float*)alloc((size_t)3 * NF * 4);
    float* vv    = (float*)alloc((size_t)3 * NF * 4);
    float* vnorm = (float*)alloc((size_t)NA * F * 4);     // readout temp
    float* stk   = (float*)alloc((size_t)NA * 256 * 4);
    int* cnt  = (int*)alloc((size_t)NA * 4);
    int* offs = (int*)alloc((size_t)(NA + 1) * 4);
    int* cur  = (int*)alloc((size_t)NA * 4);
    int* perm = (int*)alloc((size_t)NE * 4);

    // geometry + CSR (once)
    geom_kernel<<<(NE + 255) / 256, 256, 0, stream>>>(xyz, nbrs, edata);
    hipMemsetAsync(cnt, 0, (size_t)NA * 4, stream);
    hist_kernel<<<(NE + 255) / 256, 256, 0, stream>>>(nbrs, cnt);
    scan_kernel<<<1, 1024, 0, stream>>>(cnt, offs);
    hipMemsetAsync(cur, 0, (size_t)NA * 4, stream);
    fill_kernel<<<(NE + 255) / 256, 256, 0, stream>>>(nbrs, offs, cur, perm);

    // init state
    hipMemsetAsync(vA, 0, (size_t)3 * NF * 4, stream);
    embed_kernel<<<(NA * F + 255) / 256, 256, 0, stream>>>(z, embed, s);

    const int GX = (NA + 127) / 128;  // 157
    const int EW = (NA * F + 255) / 256;
    for (int l = 0; l < 3; l++) {
        gemm_kernel<1><<<dim3(GX, 2), 256, 0, stream>>>(s, msg_W1 + (size_t)l * F * F,
                                                        msg_b1 + (size_t)l * F, hid, 128, 128);
        gemm_kernel<0><<<dim3(GX, 6), 256, 0, stream>>>(hid, msg_W2 + (size_t)l * F * 384,
                                                        msg_b2 + (size_t)l * 384, phi, 128, 384);
        msg_kernel<<<NA, 128, 0, stream>>>(phi, edata, nbrs, offs, perm,
                                           msg_Wd + (size_t)l * 20 * 384, msg_bd + (size_t)l * 384,
                                           vA, vB, s);
        gemm_uvvv_kernel<<<dim3(GX, 2, 6), 256, 0, stream>>>(vB, upd_U + (size_t)l * F * F,
                                                             upd_V + (size_t)l * F * F, uv, vv);
        stack_kernel<<<EW, 256, 0, stream>>>(s, vv, stk);
        gemm_kernel<1><<<dim3(GX, 2), 256, 0, stream>>>(stk, upd_Ws1 + (size_t)l * 256 * 128,
                                                        upd_bs1 + (size_t)l * F, hid, 256, 128);
        gemm_kernel<0><<<dim3(GX, 6), 256, 0, stream>>>(hid, upd_Ws2 + (size_t)l * F * 384,
                                                        upd_bs2 + (size_t)l * 384, phi, 128, 384);
        update_kernel<<<EW, 256, 0, stream>>>(phi, uv, vv, vB, vA, s);
    }

    // readout
    gemm_kernel<1><<<dim3(GX, 1), 256, 0, stream>>>(s, ro_W1, ro_b1, hid, 128, 64);
    gemm_kernel<0><<<dim3(GX, 1), 256, 0, stream>>>(hid, ro_W2, ro_b2, vnorm, 64, 64);
    gemm_kernel<2><<<dim3(GX, 2), 256, 0, stream>>>(vnorm, fc_W1, fc_b1, stk, 64, 128);
    gemm_kernel<2><<<dim3(GX, 2), 256, 0, stream>>>(stk, fc_W2, fc_b2, hid, 128, 128);
    head_kernel<<<NA / 4, 256, 0, stream>>>(hid, fc_Wo, fc_bo, out);
}

// Round 2
// 1013.754 us; speedup vs baseline: 1.4788x; 1.4788x over previous
//
#include <hip/hip_runtime.h>
#include <math.h>

static const int NA = 20000;
static const int NE = 320000;
static const int F  = 128;
static const long NF = (long)NA * F;   // 2,560,000

// ---------------------------------------------------------------- geometry
// edata layout per edge (24 floats): [fc, ux, uy, uz, rbf0..rbf19] where
// rbf_k = sin((k+1)*pi*d/5)/d * fc (fc folded in). Only written for ACTIVE
// edges (d < 5): inactive edges contribute exactly 0 (w_s = (..)*fc = 0
// -> s0=s1=s2=0 -> ds=dv=0) and are skipped everywhere downstream.
__global__ void geom_kernel(const float* __restrict__ xyz, const int* __restrict__ nbrs,
                            float* __restrict__ edata, int* __restrict__ act) {
    int e = blockIdx.x * 256 + threadIdx.x;
    if (e >= NE) return;
    int i = nbrs[2 * e], j = nbrs[2 * e + 1];
    float xi = xyz[3 * i], yi = xyz[3 * i + 1], zi = xyz[3 * i + 2];
    float xj = xyz[3 * j], yj = xyz[3 * j + 1], zj = xyz[3 * j + 2];
    float rx = xj - xi, ry = yj - yi, rz = zj - zi;
    float d2 = rx * rx + ry * ry + rz * rz + 1e-15f;
    float d = sqrtf(d2);
    if (d >= 5.0f) { act[e] = 0; return; }
    act[e] = 1;
    float inv = 1.0f / d;
    float fc = 0.5f * (cosf(d * (float)M_PI / 5.0f) + 1.0f);
    float* ed = edata + (size_t)e * 24;
    ed[0] = fc; ed[1] = rx * inv; ed[2] = ry * inv; ed[3] = rz * inv;
    float x = d * (float)M_PI / 5.0f;
    float s1 = sinf(x), c1 = cosf(x);
    float skm1 = 0.f, sk = s1;
    float twoc = 2.f * c1;
    float scale = inv * fc;
    #pragma unroll
    for (int k = 0; k < 20; k++) {
        ed[4 + k] = sk * scale;
        float skp1 = twoc * sk - skm1;
        skm1 = sk; sk = skp1;
    }
}

// ---------------------------------------------------------------- CSR build (active edges only)
__global__ void hist_kernel(const int* __restrict__ nbrs, const int* __restrict__ act,
                            int* __restrict__ cnt) {
    int e = blockIdx.x * 256 + threadIdx.x;
    if (e < NE && act[e]) atomicAdd(&cnt[nbrs[2 * e]], 1);
}

__global__ __launch_bounds__(1024) void scan_kernel(const int* __restrict__ cnt, int* __restrict__ offs) {
    __shared__ int sh[1024];
    const int CH = 20;                       // 1024*20 = 20480 >= NA
    int t = threadIdx.x;
    int base = t * CH;
    int c[CH];
    int tot = 0;
    #pragma unroll
    for (int k = 0; k < CH; k++) {
        int idx = base + k;
        c[k] = (idx < NA) ? cnt[idx] : 0;
        tot += c[k];
    }
    sh[t] = tot;
    __syncthreads();
    for (int o = 1; o < 1024; o <<= 1) {
        int v = (t >= o) ? sh[t - o] : 0;
        __syncthreads();
        sh[t] += v;
        __syncthreads();
    }
    int run = sh[t] - tot;                   // exclusive prefix of this chunk
    #pragma unroll
    for (int k = 0; k < CH; k++) {
        int idx = base + k;
        if (idx < NA) offs[idx] = run;
        run += c[k];
    }
    if (t == 1023) offs[NA] = sh[1023];
}

// compact active edges into CSR slot order: jc[q], edc[q*24..]
__global__ void fill_kernel(const int* __restrict__ nbrs, const int* __restrict__ act,
                            const int* __restrict__ offs, int* __restrict__ cur,
                            const float* __restrict__ edata,
                            int* __restrict__ jc, float* __restrict__ edc) {
    int e = blockIdx.x * 256 + threadIdx.x;
    if (e >= NE || !act[e]) return;
    int i = nbrs[2 * e];
    int q = offs[i] + atomicAdd(&cur[i], 1);
    jc[q] = nbrs[2 * e + 1];
    const float4* src = (const float4*)(edata + (size_t)e * 24);
    float4* dst = (float4*)(edc + (size_t)q * 24);
    #pragma unroll
    for (int k = 0; k < 6; k++) dst[k] = src[k];
}

// ---------------------------------------------------------------- embed
__global__ void embed_kernel(const int* __restrict__ z, const float* __restrict__ embed,
                             float* __restrict__ s) {
    int idx = blockIdx.x * 256 + threadIdx.x;
    if (idx >= NA * F) return;
    int n = idx >> 7, f = idx & 127;
    s[idx] = embed[z[n] * F + f];
}

// ---------------------------------------------------------------- activations
__device__ __forceinline__ float epilogue_act(float x, int act) {
    if (act == 1) return x / (1.0f + expf(-x));
    if (act == 2) return fmaxf(x, 0.0f);
    return x;
}

// ---------------------------------------------------------------- GEMM 128x128, BK=32, 8x8 microtile
// A-tile stored TRANSPOSED in LDS -> inner loop is 4x ds_read_b128 per 64 FMA.
__device__ __forceinline__ void gemm128_body(float* smem,
                                             const float* __restrict__ A, const float* __restrict__ W,
                                             const float* __restrict__ bias, float* __restrict__ C,
                                             int K, int Cout, int c0, int act) {
    float (*At)[132] = (float(*)[132])smem;               // [k][m] 32x132
    float (*Bs)[132] = (float(*)[132])(smem + 32 * 132);  // [k][n] 32x132
    int tid = threadIdx.x;
    int tx = tid & 15, ty = tid >> 4;                     // col-block, row-block
    int r0 = blockIdx.x * 128;
    float acc[8][8];
    #pragma unroll
    for (int a = 0; a < 8; a++)
        #pragma unroll
        for (int b = 0; b < 8; b++) acc[a][b] = 0.f;

    for (int k0 = 0; k0 < K; k0 += 32) {
        // stage A (128 rows x 32 k): thread loads 4 float4 along K, scatters transposed
        {
            int kq = (tid & 7) * 4;          // 0..28
            int rbase = (tid >> 3) * 4;      // 0..124
            #pragma unroll
            for (int q = 0; q < 4; q++) {
                int row = rbase + q;
                int gr = r0 + row;
                float4 v = make_float4(0.f, 0.f, 0.f, 0.f);
                if (gr < NA) v = *(const float4*)(A + (size_t)gr * K + k0 + kq);
                At[kq + 0][row] = v.x; At[kq + 1][row] = v.y;
                At[kq + 2][row] = v.z; At[kq + 3][row] = v.w;
            }
        }
        // stage B (32 k x 128 cols): contiguous float4 in, float4 out
        {
            int col = (tid & 31) * 4;
            int kbase = (tid >> 5) * 4;      // 0..28
            #pragma unroll
            for (int q = 0; q < 4; q++) {
                int kk = kbase + q;
                float4 v = *(const float4*)(W + (size_t)(k0 + kk) * Cout + c0 + col);
                *(float4*)(&Bs[kk][col]) = v;
            }
        }
        __syncthreads();
        #pragma unroll 8
        for (int kk = 0; kk < 32; ++kk) {
            float4 a0 = *(const float4*)(&At[kk][ty * 8]);
            float4 a1 = *(const float4*)(&At[kk][ty * 8 + 4]);
            float4 b0 = *(const float4*)(&Bs[kk][tx * 8]);
            float4 b1 = *(const float4*)(&Bs[kk][tx * 8 + 4]);
            float av[8] = {a0.x, a0.y, a0.z, a0.w, a1.x, a1.y, a1.z, a1.w};
            float bv[8] = {b0.x, b0.y, b0.z, b0.w, b1.x, b1.y, b1.z, b1.w};
            #pragma unroll
            for (int ri = 0; ri < 8; ri++)
                #pragma unroll
                for (int ci = 0; ci < 8; ci++)
                    acc[ri][ci] += av[ri] * bv[ci];
        }
        __syncthreads();
    }
    // epilogue
    int gcb = c0 + tx * 8;
    float bb[8];
    #pragma unroll
    for (int ci = 0; ci < 8; ci++) bb[ci] = bias ? bias[gcb + ci] : 0.f;
    #pragma unroll
    for (int ri = 0; ri < 8; ri++) {
        int gr = r0 + ty * 8 + ri;
        if (gr < NA) {
            float4 o0, o1;
            o0.x = epilogue_act(acc[ri][0] + bb[0], act);
            o0.y = epilogue_act(acc[ri][1] + bb[1], act);
            o0.z = epilogue_act(acc[ri][2] + bb[2], act);
            o0.w = epilogue_act(acc[ri][3] + bb[3], act);
            o1.x = epilogue_act(acc[ri][4] + bb[4], act);
            o1.y = epilogue_act(acc[ri][5] + bb[5], act);
            o1.z = epilogue_act(acc[ri][6] + bb[6], act);
            o1.w = epilogue_act(acc[ri][7] + bb[7], act);
            *(float4*)(C + (size_t)gr * Cout + gcb) = o0;
            *(float4*)(C + (size_t)gr * Cout + gcb + 4) = o1;
        }
    }
}

template<int ACT>
__global__ __launch_bounds__(256) void gemm128_kernel(const float* __restrict__ A, const float* __restrict__ W,
                                                      const float* __restrict__ bias, float* __restrict__ C,
                                                      int K, int Cout) {
    __shared__ float smem[2 * 32 * 132];
    gemm128_body(smem, A, W, bias, C, K, Cout, blockIdx.y * 128, ACT);
}

// batched u_v / v_v: grid.z = 6 -> (mat = z/3 in {U,V}, d = z%3)
__global__ __launch_bounds__(256) void gemm_uvvv_kernel(const float* __restrict__ vB,
                                                        const float* __restrict__ U, const float* __restrict__ V,
                                                        float* __restrict__ uv, float* __restrict__ vv) {
    __shared__ float smem[2 * 32 * 132];
    int zz = blockIdx.z;
    int d = zz % 3;
    const float* A = vB + (size_t)d * NF;
    const float* W = (zz < 3) ? U : V;
    float* C = ((zz < 3) ? uv : vv) + (size_t)d * NF;
    gemm128_body(smem, A, W, nullptr, C, 128, 128, 0, 0);
}

// ---------------------------------------------------------------- old 64-col GEMM (readout, Cout<=64)
__device__ __forceinline__ void gemm_body(float* smem,
                                          const float* __restrict__ A, const float* __restrict__ W,
                                          const float* __restrict__ bias, float* __restrict__ C,
                                          int K, int Cout, int act) {
    float (*As)[65] = (float(*)[65])smem;                 // 128 x 65
    float (*Ws)[64] = (float(*)[64])(smem + 128 * 65);    // 64 x 64
    int tid = threadIdx.x;
    int tx = tid & 15, ty = tid >> 4;
    int r0 = blockIdx.x * 128;
    int c0 = blockIdx.y * 64;
    float acc[8][4];
    #pragma unroll
    for (int a = 0; a < 8; a++)
        #pragma unroll
        for (int b = 0; b < 4; b++) acc[a][b] = 0.f;

    for (int k0 = 0; k0 < K; k0 += 64) {
        #pragma unroll
        for (int q = 0; q < 8; q++) {
            int row = ty + q * 16;
            int col = tx * 4;
            int gr = r0 + row;
            float4 va = make_float4(0.f, 0.f, 0.f, 0.f);
            if (gr < NA) va = *(const float4*)(A + (size_t)gr * K + k0 + col);
            As[row][col + 0] = va.x; As[row][col + 1] = va.y;
            As[row][col + 2] = va.z; As[row][col + 3] = va.w;
        }
        #pragma unroll
        for (int q = 0; q < 4; q++) {
            int row = ty + q * 16;
            int col = tx * 4;
            int gc = c0 + col;
            float4 vw = make_float4(0.f, 0.f, 0.f, 0.f);
            if (gc < Cout) vw = *(const float4*)(W + (size_t)(k0 + row) * Cout + gc);
            *(float4*)(&Ws[row][col]) = vw;
        }
        __syncthreads();
        #pragma unroll 8
        for (int kk = 0; kk < 64; ++kk) {
            float4 b = *(const float4*)(&Ws[kk][tx * 4]);
            #pragma unroll
            for (int ri = 0; ri < 8; ++ri) {
                float a = As[ty * 8 + ri][kk];
                acc[ri][0] += a * b.x; acc[ri][1] += a * b.y;
                acc[ri][2] += a * b.z; acc[ri][3] += a * b.w;
            }
        }
        __syncthreads();
    }
    int gc = c0 + tx * 4;
    if (gc < Cout) {
        float bb0 = 0.f, bb1 = 0.f, bb2 = 0.f, bb3 = 0.f;
        if (bias) { bb0 = bias[gc]; bb1 = bias[gc + 1]; bb2 = bias[gc + 2]; bb3 = bias[gc + 3]; }
        #pragma unroll
        for (int ri = 0; ri < 8; ri++) {
            int gr = r0 + ty * 8 + ri;
            if (gr < NA) {
                float4 o;
                o.x = epilogue_act(acc[ri][0] + bb0, act);
                o.y = epilogue_act(acc[ri][1] + bb1, act);
                o.z = epilogue_act(acc[ri][2] + bb2, act);
                o.w = epilogue_act(acc[ri][3] + bb3, act);
                *(float4*)(C + (size_t)gr * Cout + gc) = o;
            }
        }
    }
}

template<int ACT>
__global__ __launch_bounds__(256) void gemm_kernel(const float* __restrict__ A, const float* __restrict__ W,
                                                   const float* __restrict__ bias, float* __restrict__ C,
                                                   int K, int Cout) {
    __shared__ float smem[128 * 65 + 64 * 64];
    gemm_body(smem, A, W, bias, C, K, Cout, ACT);
}

// ---------------------------------------------------------------- message + aggregation
// one block (128 threads) per atom i; compacted active-edge CSR
__global__ __launch_bounds__(128) void msg_kernel(
    const float* __restrict__ phi, const float* __restrict__ edc,
    const int* __restrict__ jc, const int* __restrict__ offs,
    const float* __restrict__ Wd, const float* __restrict__ bd,
    const float* __restrict__ vin, float* __restrict__ vout, float* __restrict__ s) {
    int i = blockIdx.x;
    int f = threadIdx.x;
    float wd0[20], wd1[20], wd2[20];
    #pragma unroll
    for (int k = 0; k < 20; k++) {
        wd0[k] = Wd[k * 384 + f];
        wd1[k] = Wd[k * 384 + 128 + f];
        wd2[k] = Wd[k * 384 + 256 + f];
    }
    float b0 = bd[f], b1 = bd[128 + f], b2 = bd[256 + f];
    float accS = 0.f, aV0 = 0.f, aV1 = 0.f, aV2 = 0.f;
    int p0 = offs[i], p1 = offs[i + 1];
    for (int p = p0; p < p1; ++p) {
        int j = jc[p];
        const float4* ed = (const float4*)(edc + (size_t)p * 24);
        float4 q0 = ed[0], q1 = ed[1], q2 = ed[2], q3 = ed[3], q4 = ed[4], q5 = ed[5];
        float fc = q0.x, ux = q0.y, uy = q0.z, uz = q0.w;
        float rb[20];
        rb[0]=q1.x; rb[1]=q1.y; rb[2]=q1.z; rb[3]=q1.w;
        rb[4]=q2.x; rb[5]=q2.y; rb[6]=q2.z; rb[7]=q2.w;
        rb[8]=q3.x; rb[9]=q3.y; rb[10]=q3.z; rb[11]=q3.w;
        rb[12]=q4.x; rb[13]=q4.y; rb[14]=q4.z; rb[15]=q4.w;
        rb[16]=q5.x; rb[17]=q5.y; rb[18]=q5.z; rb[19]=q5.w;
        float w0 = b0 * fc, w1 = b1 * fc, w2 = b2 * fc;
        #pragma unroll
        for (int k = 0; k < 20; k++) {
            w0 += rb[k] * wd0[k];
            w1 += rb[k] * wd1[k];
            w2 += rb[k] * wd2[k];
        }
        const float* pj = phi + (size_t)j * 384;
        float i0 = pj[f] * w0, i1 = pj[128 + f] * w1, i2 = pj[256 + f] * w2;
        size_t jb = (size_t)j * F + f;
        accS += i1;
        aV0 += i2 * ux + i0 * vin[jb];
        aV1 += i2 * uy + i0 * vin[NF + jb];
        aV2 += i2 * uz + i0 * vin[2 * NF + jb];
    }
    size_t ib = (size_t)i * F + f;
    s[ib] += accS;
    vout[ib]          = vin[ib] + aV0;
    vout[NF + ib]     = vin[NF + ib] + aV1;
    vout[2 * NF + ib] = vin[2 * NF + ib] + aV2;
}

// ---------------------------------------------------------------- elementwise
__global__ void stack_kernel(const float* __restrict__ s, const float* __restrict__ vv,
                             float* __restrict__ stk) {
    int idx = blockIdx.x * 256 + threadIdx.x;
    if (idx >= NA * F) return;
    int n = idx >> 7, f = idx & 127;
    float a = vv[idx], b = vv[NF + idx], c = vv[2 * NF + idx];
    stk[(size_t)n * 256 + f] = s[idx];
    stk[(size_t)n * 256 + 128 + f] = sqrtf(a * a + b * b + c * c + 1e-15f);
}

__global__ void update_kernel(const float* __restrict__ split, const float* __restrict__ uv,
                              const float* __restrict__ vv, const float* __restrict__ vin,
                              float* __restrict__ vout, float* __restrict__ s) {
    int idx = blockIdx.x * 256 + threadIdx.x;
    if (idx >= NA * F) return;
    int n = idx >> 7, f = idx & 127;
    const float* sp = split + (size_t)n * 384;
    float avv = sp[f], asv = sp[128 + f], ass = sp[256 + f];
    float dot = 0.f;
    #pragma unroll
    for (int d = 0; d < 3; d++) {
        float u = uv[d * NF + idx];
        vout[d * NF + idx] = vin[d * NF + idx] + u * avv;
        dot += u * vv[d * NF + idx];
    }
    s[idx] += dot * asv + ass;
}

// ---------------------------------------------------------------- head
__global__ __launch_bounds__(256) void head_kernel(const float* __restrict__ h,
                                                   const float* __restrict__ Wo,
                                                   const float* __restrict__ bo,
                                                   float* __restrict__ out) {
    int n = blockIdx.x * 4 + (threadIdx.x >> 6);
    int lane = threadIdx.x & 63;
    if (n >= NA) return;
    float p = h[(size_t)n * 128 + lane] * Wo[lane] + h[(size_t)n * 128 + 64 + lane] * Wo[64 + lane];
    #pragma unroll
    for (int o = 32; o > 0; o >>= 1) p += __shfl_down(p, o);
    if (lane == 0) out[n] = p + bo[0];
}

// ---------------------------------------------------------------- host
extern "C" void kernel_launch(void* const* d_in, const int* in_sizes, int n_in,
                              void* d_out, int out_size, void* d_ws, size_t ws_size,
                              hipStream_t stream) {
    const float* xyz    = (const float*)d_in[0];
    const int*   z      = (const int*)d_in[1];
    const int*   nbrs   = (const int*)d_in[2];
    const float* embed  = (const float*)d_in[3];
    const float* msg_W1 = (const float*)d_in[4];
    const float* msg_b1 = (const float*)d_in[5];
    const float* msg_W2 = (const float*)d_in[6];
    const float* msg_b2 = (const float*)d_in[7];
    const float* msg_Wd = (const float*)d_in[8];
    const float* msg_bd = (const float*)d_in[9];
    const float* upd_U  = (const float*)d_in[10];
    const float* upd_V  = (const float*)d_in[11];
    const float* upd_Ws1= (const float*)d_in[12];
    const float* upd_bs1= (const float*)d_in[13];
    const float* upd_Ws2= (const float*)d_in[14];
    const float* upd_bs2= (const float*)d_in[15];
    const float* ro_W1  = (const float*)d_in[16];
    const float* ro_b1  = (const float*)d_in[17];
    const float* ro_W2  = (const float*)d_in[18];
    const float* ro_b2  = (const float*)d_in[19];
    const float* fc_W1  = (const float*)d_in[20];
    const float* fc_b1  = (const float*)d_in[21];
    const float* fc_W2  = (const float*)d_in[22];
    const float* fc_b2  = (const float*)d_in[23];
    const float* fc_Wo  = (const float*)d_in[24];
    const float* fc_bo  = (const float*)d_in[25];
    float* out = (float*)d_out;

    char* ws = (char*)d_ws;
    size_t off = 0;
    auto alloc = [&](size_t nbytes) -> char* {
        char* p = ws + off;
        off += (nbytes + 255) / 256 * 256;
        return p;
    };
    float* edata = (float*)alloc((size_t)NE * 24 * 4);   // temp (by original edge id)
    float* edc   = (float*)alloc((size_t)NE * 24 * 4);   // compacted (CSR slot order)
    float* s     = (float*)alloc((size_t)NA * F * 4);
    float* vA    = (float*)alloc((size_t)3 * NF * 4);
    float* vB    = (float*)alloc((size_t)3 * NF * 4);
    float* phi   = (float*)alloc((size_t)NA * 384 * 4);  // reused as split
    float* hid   = (float*)alloc((size_t)NA * F * 4);
    float* uv    = (float*)alloc((size_t)3 * NF * 4);
    float* vv    = (float*)alloc((size_t)3 * NF * 4);
    float* vnorm = (float*)alloc((size_t)NA * F * 4);    // readout temp
    float* stk   = (float*)alloc((size_t)NA * 256 * 4);
    int* act  = (int*)alloc((size_t)NE * 4);
    int* cnt  = (int*)alloc((size_t)NA * 4);
    int* offs = (int*)alloc((size_t)(NA + 1) * 4);
    int* cur  = (int*)alloc((size_t)NA * 4);
    int* jc   = (int*)alloc((size_t)NE * 4);

    // geometry + active-edge CSR (once)
    geom_kernel<<<(NE + 255) / 256, 256, 0, stream>>>(xyz, nbrs, edata, act);
    hipMemsetAsync(cnt, 0, (size_t)NA * 4, stream);
    hist_kernel<<<(NE + 255) / 256, 256, 0, stream>>>(nbrs, act, cnt);
    scan_kernel<<<1, 1024, 0, stream>>>(cnt, offs);
    hipMemsetAsync(cur, 0, (size_t)NA * 4, stream);
    fill_kernel<<<(NE + 255) / 256, 256, 0, stream>>>(nbrs, act, offs, cur, edata, jc, edc);

    // init state
    hipMemsetAsync(vA, 0, (size_t)3 * NF * 4, stream);
    embed_kernel<<<(NA * F + 255) / 256, 256, 0, stream>>>(z, embed, s);

    const int GX = (NA + 127) / 128;  // 157
    const int EW = (NA * F + 255) / 256;
    for (int l = 0; l < 3; l++) {
        gemm128_kernel<1><<<dim3(GX, 1), 256, 0, stream>>>(s, msg_W1 + (size_t)l * F * F,
                                                           msg_b1 + (size_t)l * F, hid, 128, 128);
        gemm128_kernel<0><<<dim3(GX, 3), 256, 0, stream>>>(hid, msg_W2 + (size_t)l * F * 384,
                                                           msg_b2 + (size_t)l * 384, phi, 128, 384);
        msg_kernel<<<NA, 128, 0, stream>>>(phi, edc, jc, offs,
                                           msg_Wd + (size_t)l * 20 * 384, msg_bd + (size_t)l * 384,
                                           vA, vB, s);
        gemm_uvvv_kernel<<<dim3(GX, 1, 6), 256, 0, stream>>>(vB, upd_U + (size_t)l * F * F,
                                                             upd_V + (size_t)l * F * F, uv, vv);
        stack_kernel<<<EW, 256, 0, stream>>>(s, vv, stk);
        gemm128_kernel<1><<<dim3(GX, 1), 256, 0, stream>>>(stk, upd_Ws1 + (size_t)l * 256 * 128,
                                                           upd_bs1 + (size_t)l * F, hid, 256, 128);
        gemm128_kernel<0><<<dim3(GX, 3), 256, 0, stream>>>(hid, upd_Ws2 + (size_t)l * F * 384,
                                                           upd_bs2 + (size_t)l * 384, phi, 128, 384);
        update_kernel<<<EW, 256, 0, stream>>>(phi, uv, vv, vB, vA, s);
    }

    // readout
    gemm_kernel<1><<<dim3(GX, 1), 256, 0, stream>>>(s, ro_W1, ro_b1, hid, 128, 64);
    gemm_kernel<0><<<dim3(GX, 1), 256, 0, stream>>>(hid, ro_W2, ro_b2, vnorm, 64, 64);
    gemm128_kernel<2><<<dim3(GX, 1), 256, 0, stream>>>(vnorm, fc_W1, fc_b1, stk, 64, 128);
    gemm128_kernel<2><<<dim3(GX, 1), 256, 0, stream>>>(stk, fc_W2, fc_b2, hid, 128, 128);
    head_kernel<<<NA / 4, 256, 0, stream>>>(hid, fc_Wo, fc_bo, out);
}

// Round 5
// 723.458 us; speedup vs baseline: 2.0722x; 1.4013x over previous
//
#include <hip/hip_runtime.h>
#include <math.h>

static const int NA = 20000;
static const int NE = 320000;
static const int F  = 128;
static const long NF = (long)NA * F;   // 2,560,000

typedef short short8 __attribute__((ext_vector_type(8)));   // 8 bf16 (4 VGPRs)
typedef float f32x4  __attribute__((ext_vector_type(4)));

// ---------------------------------------------------------------- geometry
__global__ void geom_kernel(const float* __restrict__ xyz, const int* __restrict__ nbrs,
                            float* __restrict__ edata, int* __restrict__ act) {
    int e = blockIdx.x * 256 + threadIdx.x;
    if (e >= NE) return;
    int i = nbrs[2 * e], j = nbrs[2 * e + 1];
    float xi = xyz[3 * i], yi = xyz[3 * i + 1], zi = xyz[3 * i + 2];
    float xj = xyz[3 * j], yj = xyz[3 * j + 1], zj = xyz[3 * j + 2];
    float rx = xj - xi, ry = yj - yi, rz = zj - zi;
    float d2 = rx * rx + ry * ry + rz * rz + 1e-15f;
    float d = sqrtf(d2);
    if (d >= 5.0f) { act[e] = 0; return; }
    act[e] = 1;
    float inv = 1.0f / d;
    float fc = 0.5f * (cosf(d * (float)M_PI / 5.0f) + 1.0f);
    float* ed = edata + (size_t)e * 24;
    ed[0] = fc; ed[1] = rx * inv; ed[2] = ry * inv; ed[3] = rz * inv;
    float x = d * (float)M_PI / 5.0f;
    float s1 = sinf(x), c1 = cosf(x);
    float skm1 = 0.f, sk = s1;
    float twoc = 2.f * c1;
    float scale = inv * fc;
    #pragma unroll
    for (int k = 0; k < 20; k++) {
        ed[4 + k] = sk * scale;
        float skp1 = twoc * sk - skm1;
        skm1 = sk; sk = skp1;
    }
}

// ---------------------------------------------------------------- CSR build (active edges only)
__global__ void hist_kernel(const int* __restrict__ nbrs, const int* __restrict__ act,
                            int* __restrict__ cnt) {
    int e = blockIdx.x * 256 + threadIdx.x;
    if (e < NE && act[e]) atomicAdd(&cnt[nbrs[2 * e]], 1);
}

__global__ __launch_bounds__(1024) void scan_kernel(const int* __restrict__ cnt, int* __restrict__ offs) {
    __shared__ int sh[1024];
    const int CH = 20;
    int t = threadIdx.x;
    int base = t * CH;
    int c[CH];
    int tot = 0;
    #pragma unroll
    for (int k = 0; k < CH; k++) {
        int idx = base + k;
        c[k] = (idx < NA) ? cnt[idx] : 0;
        tot += c[k];
    }
    sh[t] = tot;
    __syncthreads();
    for (int o = 1; o < 1024; o <<= 1) {
        int v = (t >= o) ? sh[t - o] : 0;
        __syncthreads();
        sh[t] += v;
        __syncthreads();
    }
    int run = sh[t] - tot;
    #pragma unroll
    for (int k = 0; k < CH; k++) {
        int idx = base + k;
        if (idx < NA) offs[idx] = run;
        run += c[k];
    }
    if (t == 1023) offs[NA] = sh[1023];
}

__global__ void fill_kernel(const int* __restrict__ nbrs, const int* __restrict__ act,
                            const int* __restrict__ offs, int* __restrict__ cur,
                            const float* __restrict__ edata,
                            int* __restrict__ jc, float* __restrict__ edc) {
    int e = blockIdx.x * 256 + threadIdx.x;
    if (e >= NE || !act[e]) return;
    int i = nbrs[2 * e];
    int q = offs[i] + atomicAdd(&cur[i], 1);
    jc[q] = nbrs[2 * e + 1];
    const float4* src = (const float4*)(edata + (size_t)e * 24);
    float4* dst = (float4*)(edc + (size_t)q * 24);
    #pragma unroll
    for (int k = 0; k < 6; k++) dst[k] = src[k];
}

// ---------------------------------------------------------------- embed (+ split)
__global__ void embed_kernel(const int* __restrict__ z, const float* __restrict__ embed,
                             float* __restrict__ s, __bf16* __restrict__ sh_, __bf16* __restrict__ sl_) {
    int idx = blockIdx.x * 256 + threadIdx.x;
    if (idx >= NA * F) return;
    int n = idx >> 7, f = idx & 127;
    float v = embed[z[n] * F + f];
    s[idx] = v;
    __bf16 h = (__bf16)v;
    sh_[idx] = h; sl_[idx] = (__bf16)(v - (float)h);
}

// ---------------------------------------------------------------- weight transpose + split
// dst layout [N][K] bf16 hi/lo, segments per layer:
// W1@0(16384) W2@16384(49152) U@65536 V@81920 Ws1@98304(32768) Ws2@131072(49152), total 180224/layer
__global__ void wconv_kernel(const float* __restrict__ W1, const float* __restrict__ W2,
                             const float* __restrict__ U, const float* __restrict__ V,
                             const float* __restrict__ Ws1, const float* __restrict__ Ws2,
                             __bf16* __restrict__ wh, __bf16* __restrict__ wl) {
    int g = blockIdx.x * 256 + threadIdx.x;
    if (g >= 3 * 180224) return;
    int lay = g / 180224, o = g - lay * 180224;
    const float* src; int K, N, idx;
    if (o < 16384)       { src = W1  + (size_t)lay * 16384; K = 128; N = 128; idx = o; }
    else if (o < 65536)  { src = W2  + (size_t)lay * 49152; K = 128; N = 384; idx = o - 16384; }
    else if (o < 81920)  { src = U   + (size_t)lay * 16384; K = 128; N = 128; idx = o - 65536; }
    else if (o < 98304)  { src = V   + (size_t)lay * 16384; K = 128; N = 128; idx = o - 81920; }
    else if (o < 131072) { src = Ws1 + (size_t)lay * 32768; K = 256; N = 128; idx = o - 98304; }
    else                 { src = Ws2 + (size_t)lay * 49152; K = 128; N = 384; idx = o - 131072; }
    int n = idx / K, k = idx - n * K;
    float v = src[(size_t)k * N + n];
    __bf16 h = (__bf16)v;
    wh[g] = h; wl[g] = (__bf16)(v - (float)h);
}

// ---------------------------------------------------------------- split-bf16 MFMA GEMM
// C = A*B: A fp32 repr by (Ah+Al) bf16 [M][K]; B by Wt (Bh+Bl) bf16 [N][K].
// 128x128 tile, BK=64, 4 waves 2x2, 16x16x32 MFMA, 3 products (hh, hl, lh).
// LDS: 4 comps x [128 rows][64 bf16] = 64KB. 16B slots XOR-swizzled on the
// WRITE side (slot ^= row&7) and identically on the read side (T2 involution).
template<int ACT, int MODE>   // ACT: 0 none, 1 silu. MODE: 0 fp32 out, 1 split bf16 out
__device__ __forceinline__ void mgemm_body(char* ldsb,
    const __bf16* __restrict__ Ah, const __bf16* __restrict__ Al,
    const __bf16* __restrict__ Bh, const __bf16* __restrict__ Bl,
    const float* __restrict__ bias, int K, int N, int c0,
    float* __restrict__ Cf, __bf16* __restrict__ Ch, __bf16* __restrict__ Cl) {
    int tid = threadIdx.x;
    int w = tid >> 6, l = tid & 63;
    int r0 = blockIdx.x * 128;

    int srow = tid >> 3, sl = tid & 7;

    int wr = w >> 1, wc = w & 1;
    int lrow = l & 15, lk = l >> 4;
    uint32_t arow[4], axor[4], brow[4], bxor[4];
    #pragma unroll
    for (int m = 0; m < 4; m++) {
        int row = wr * 64 + m * 16 + lrow;
        arow[m] = (uint32_t)row * 128u; axor[m] = (uint32_t)((row & 7) << 4);
    }
    #pragma unroll
    for (int n = 0; n < 4; n++) {
        int row = wc * 64 + n * 16 + lrow;
        brow[n] = (uint32_t)row * 128u; bxor[n] = (uint32_t)((row & 7) << 4);
    }

    f32x4 acc[4][4];
    #pragma unroll
    for (int m = 0; m < 4; m++)
        #pragma unroll
        for (int n = 0; n < 4; n++) acc[m][n] = (f32x4){0.f, 0.f, 0.f, 0.f};

    const char* pAh = (const char*)Ah;
    const char* pAl = (const char*)Al;
    const char* pBh = (const char*)Bh;
    const char* pBl = (const char*)Bl;

    for (int k0 = 0; k0 < K; k0 += 64) {
        #pragma unroll
        for (int t = 0; t < 4; t++) {
            int row = srow + t * 32;
            uint32_t dst = (uint32_t)row * 128u + (uint32_t)(((sl ^ (row & 7)) << 4));
            int ga = min(r0 + row, NA - 1);
            size_t soA = ((size_t)ga * K + k0 + sl * 8) * 2;
            size_t soB = ((size_t)(c0 + row) * K + k0 + sl * 8) * 2;
            *(float4*)(ldsb + dst)         = *(const float4*)(pAh + soA);
            *(float4*)(ldsb + 16384 + dst) = *(const float4*)(pAl + soA);
            *(float4*)(ldsb + 32768 + dst) = *(const float4*)(pBh + soB);
            *(float4*)(ldsb + 49152 + dst) = *(const float4*)(pBl + soB);
        }
        __syncthreads();
        #pragma unroll
        for (int kh = 0; kh < 2; kh++) {
            uint32_t ks = (uint32_t)((kh * 4 + lk) * 16);
            short8 fah[4], fal[4], fbh[4], fbl[4];
            #pragma unroll
            for (int m = 0; m < 4; m++) {
                uint32_t ob = arow[m] + (ks ^ axor[m]);
                fah[m] = *(const short8*)(ldsb + ob);
                fal[m] = *(const short8*)(ldsb + 16384 + ob);
            }
            #pragma unroll
            for (int n = 0; n < 4; n++) {
                uint32_t ob = brow[n] + (ks ^ bxor[n]);
                fbh[n] = *(const short8*)(ldsb + 32768 + ob);
                fbl[n] = *(const short8*)(ldsb + 49152 + ob);
            }
            #pragma unroll
            for (int m = 0; m < 4; m++)
                #pragma unroll
                for (int n = 0; n < 4; n++) {
                    acc[m][n] = __builtin_amdgcn_mfma_f32_16x16x32_bf16(fah[m], fbh[n], acc[m][n], 0, 0, 0);
                    acc[m][n] = __builtin_amdgcn_mfma_f32_16x16x32_bf16(fah[m], fbl[n], acc[m][n], 0, 0, 0);
                    acc[m][n] = __builtin_amdgcn_mfma_f32_16x16x32_bf16(fal[m], fbh[n], acc[m][n], 0, 0, 0);
                }
        }
        __syncthreads();
    }

    // epilogue: C col = lane&15, row = (lane>>4)*4 + reg (m89-verified)
    #pragma unroll
    for (int n = 0; n < 4; n++) {
        int gc = c0 + wc * 64 + n * 16 + lrow;
        float bb = bias ? bias[gc] : 0.f;
        #pragma unroll
        for (int m = 0; m < 4; m++) {
            #pragma unroll
            for (int r = 0; r < 4; r++) {
                int gr = r0 + wr * 64 + m * 16 + lk * 4 + r;
                if (gr < NA) {
                    float y = acc[m][n][r] + bb;
                    if (ACT == 1) y = y / (1.f + expf(-y));
                    if (MODE == 0) {
                        Cf[(size_t)gr * N + gc] = y;
                    } else {
                        __bf16 h = (__bf16)y;
                        Ch[(size_t)gr * N + gc] = h;
                        Cl[(size_t)gr * N + gc] = (__bf16)(y - (float)h);
                    }
                }
            }
        }
    }
}

template<int ACT, int MODE>
__global__ __launch_bounds__(256, 2) void mgemm_kernel(
    const __bf16* __restrict__ Ah, const __bf16* __restrict__ Al,
    const __bf16* __restrict__ Bh, const __bf16* __restrict__ Bl,
    const float* __restrict__ bias, int K, int N,
    float* __restrict__ Cf, __bf16* __restrict__ Ch, __bf16* __restrict__ Cl) {
    __shared__ __attribute__((aligned(16))) char lds[65536];
    mgemm_body<ACT, MODE>(lds, Ah, Al, Bh, Bl, bias, K, N, blockIdx.y * 128, Cf, Ch, Cl);
}

__global__ __launch_bounds__(256, 2) void mgemm_uvvv_kernel(
    const __bf16* __restrict__ vBh, const __bf16* __restrict__ vBl,
    const __bf16* __restrict__ Uth, const __bf16* __restrict__ Utl,
    const __bf16* __restrict__ Vth, const __bf16* __restrict__ Vtl,
    float* __restrict__ uv, float* __restrict__ vv) {
    __shared__ __attribute__((aligned(16))) char lds[65536];
    int zz = blockIdx.z, d = zz % 3;
    const __bf16* Ah = vBh + (size_t)d * NF;
    const __bf16* Al = vBl + (size_t)d * NF;
    const __bf16* Bh = (zz < 3) ? Uth : Vth;
    const __bf16* Bl = (zz < 3) ? Utl : Vtl;
    float* Cf = ((zz < 3) ? uv : vv) + (size_t)d * NF;
    mgemm_body<0, 0>(lds, Ah, Al, Bh, Bl, nullptr, 128, 128, 0, Cf, nullptr, nullptr);
}

// ---------------------------------------------------------------- fp32 GEMMs for readout
__device__ __forceinline__ float epilogue_act(float x, int act) {
    if (act == 1) return x / (1.0f + expf(-x));
    if (act == 2) return fmaxf(x, 0.0f);
    return x;
}

__device__ __forceinline__ void gemm_body(float* smem,
                                          const float* __restrict__ A, const float* __restrict__ W,
                                          const float* __restrict__ bias, float* __restrict__ C,
                                          int K, int Cout, int act) {
    float (*As)[65] = (float(*)[65])smem;
    float (*Ws)[64] = (float(*)[64])(smem + 128 * 65);
    int tid = threadIdx.x;
    int tx = tid & 15, ty = tid >> 4;
    int r0 = blockIdx.x * 128;
    int c0 = blockIdx.y * 64;
    float acc[8][4];
    #pragma unroll
    for (int a = 0; a < 8; a++)
        #pragma unroll
        for (int b = 0; b < 4; b++) acc[a][b] = 0.f;

    for (int k0 = 0; k0 < K; k0 += 64) {
        #pragma unroll
        for (int q = 0; q < 8; q++) {
            int row = ty + q * 16;
            int col = tx * 4;
            int gr = r0 + row;
            float4 va = make_float4(0.f, 0.f, 0.f, 0.f);
            if (gr < NA && col < K) va = *(const float4*)(A + (size_t)gr * K + k0 + col);
            As[row][col + 0] = va.x; As[row][col + 1] = va.y;
            As[row][col + 2] = va.z; As[row][col + 3] = va.w;
        }
        #pragma unroll
        for (int q = 0; q < 4; q++) {
            int row = ty + q * 16;
            int col = tx * 4;
            int gc = c0 + col;
            float4 vw = make_float4(0.f, 0.f, 0.f, 0.f);
            if (gc < Cout && k0 + row < K) vw = *(const float4*)(W + (size_t)(k0 + row) * Cout + gc);
            *(float4*)(&Ws[row][col]) = vw;
        }
        __syncthreads();
        #pragma unroll 8
        for (int kk = 0; kk < 64; ++kk) {
            float4 b = *(const float4*)(&Ws[kk][tx * 4]);
            #pragma unroll
            for (int ri = 0; ri < 8; ++ri) {
                float a = As[ty * 8 + ri][kk];
                acc[ri][0] += a * b.x; acc[ri][1] += a * b.y;
                acc[ri][2] += a * b.z; acc[ri][3] += a * b.w;
            }
        }
        __syncthreads();
    }
    int gc = c0 + tx * 4;
    if (gc < Cout) {
        float bb0 = 0.f, bb1 = 0.f, bb2 = 0.f, bb3 = 0.f;
        if (bias) { bb0 = bias[gc]; bb1 = bias[gc + 1]; bb2 = bias[gc + 2]; bb3 = bias[gc + 3]; }
        #pragma unroll
        for (int ri = 0; ri < 8; ri++) {
            int gr = r0 + ty * 8 + ri;
            if (gr < NA) {
                float4 o;
                o.x = epilogue_act(acc[ri][0] + bb0, act);
                o.y = epilogue_act(acc[ri][1] + bb1, act);
                o.z = epilogue_act(acc[ri][2] + bb2, act);
                o.w = epilogue_act(acc[ri][3] + bb3, act);
                *(float4*)(C + (size_t)gr * Cout + gc) = o;
            }
        }
    }
}

template<int ACT>
__global__ __launch_bounds__(256) void gemm_kernel(const float* __restrict__ A, const float* __restrict__ W,
                                                   const float* __restrict__ bias, float* __restrict__ C,
                                                   int K, int Cout) {
    __shared__ float smem[128 * 65 + 64 * 64];
    gemm_body(smem, A, W, bias, C, K, Cout, ACT);
}

// ---------------------------------------------------------------- message + aggregation (split-out only)
__global__ __launch_bounds__(128) void msg_kernel(
    const float* __restrict__ phi, const float* __restrict__ edc,
    const int* __restrict__ jc, const int* __restrict__ offs,
    const float* __restrict__ Wd, const float* __restrict__ bd,
    const float* __restrict__ vin, float* __restrict__ s,
    __bf16* __restrict__ vBh, __bf16* __restrict__ vBl) {
    int i = blockIdx.x;
    int f = threadIdx.x;
    float wd0[20], wd1[20], wd2[20];
    #pragma unroll
    for (int k = 0; k < 20; k++) {
        wd0[k] = Wd[k * 384 + f];
        wd1[k] = Wd[k * 384 + 128 + f];
        wd2[k] = Wd[k * 384 + 256 + f];
    }
    float b0 = bd[f], b1 = bd[128 + f], b2 = bd[256 + f];
    float accS = 0.f, aV0 = 0.f, aV1 = 0.f, aV2 = 0.f;
    int p0 = offs[i], p1 = offs[i + 1];
    for (int p = p0; p < p1; ++p) {
        int j = jc[p];
        const float4* ed = (const float4*)(edc + (size_t)p * 24);
        float4 q0 = ed[0], q1 = ed[1], q2 = ed[2], q3 = ed[3], q4 = ed[4], q5 = ed[5];
        float fc = q0.x, ux = q0.y, uy = q0.z, uz = q0.w;
        float rb[20];
        rb[0]=q1.x; rb[1]=q1.y; rb[2]=q1.z; rb[3]=q1.w;
        rb[4]=q2.x; rb[5]=q2.y; rb[6]=q2.z; rb[7]=q2.w;
        rb[8]=q3.x; rb[9]=q3.y; rb[10]=q3.z; rb[11]=q3.w;
        rb[12]=q4.x; rb[13]=q4.y; rb[14]=q4.z; rb[15]=q4.w;
        rb[16]=q5.x; rb[17]=q5.y; rb[18]=q5.z; rb[19]=q5.w;
        float w0 = b0 * fc, w1 = b1 * fc, w2 = b2 * fc;
        #pragma unroll
        for (int k = 0; k < 20; k++) {
            w0 += rb[k] * wd0[k];
            w1 += rb[k] * wd1[k];
            w2 += rb[k] * wd2[k];
        }
        const float* pj = phi + (size_t)j * 384;
        float i0 = pj[f] * w0, i1 = pj[128 + f] * w1, i2 = pj[256 + f] * w2;
        size_t jb = (size_t)j * F + f;
        accS += i1;
        aV0 += i2 * ux + i0 * vin[jb];
        aV1 += i2 * uy + i0 * vin[NF + jb];
        aV2 += i2 * uz + i0 * vin[2 * NF + jb];
    }
    size_t ib = (size_t)i * F + f;
    s[ib] += accS;
    float o0 = vin[ib] + aV0;
    float o1 = vin[NF + ib] + aV1;
    float o2 = vin[2 * NF + ib] + aV2;
    __bf16 h0 = (__bf16)o0, h1 = (__bf16)o1, h2 = (__bf16)o2;
    vBh[ib] = h0;            vBl[ib] = (__bf16)(o0 - (float)h0);
    vBh[NF + ib] = h1;       vBl[NF + ib] = (__bf16)(o1 - (float)h1);
    vBh[2 * NF + ib] = h2;   vBl[2 * NF + ib] = (__bf16)(o2 - (float)h2);
}

// ---------------------------------------------------------------- elementwise
__global__ void stack_kernel(const float* __restrict__ s, const float* __restrict__ vv,
                             __bf16* __restrict__ stkh, __bf16* __restrict__ stkl) {
    int idx = blockIdx.x * 256 + threadIdx.x;
    if (idx >= NA * F) return;
    int n = idx >> 7, f = idx & 127;
    float a = vv[idx], b = vv[NF + idx], c = vv[2 * NF + idx];
    float sv = s[idx];
    float vn = sqrtf(a * a + b * b + c * c + 1e-15f);
    size_t o0 = (size_t)n * 256 + f;
    size_t o1 = o0 + 128;
    __bf16 h0 = (__bf16)sv, h1 = (__bf16)vn;
    stkh[o0] = h0; stkl[o0] = (__bf16)(sv - (float)h0);
    stkh[o1] = h1; stkl[o1] = (__bf16)(vn - (float)h1);
}

// v_in reconstructed from vBh+vBl (fp32 vB dropped to fit workspace)
__global__ void update_kernel(const float* __restrict__ split, const float* __restrict__ uv,
                              const float* __restrict__ vv,
                              const __bf16* __restrict__ vBh, const __bf16* __restrict__ vBl,
                              float* __restrict__ vout, float* __restrict__ s,
                              __bf16* __restrict__ sh_, __bf16* __restrict__ sl_) {
    int idx = blockIdx.x * 256 + threadIdx.x;
    if (idx >= NA * F) return;
    int n = idx >> 7, f = idx & 127;
    const float* sp = split + (size_t)n * 384;
    float avv = sp[f], asv = sp[128 + f], ass = sp[256 + f];
    float dot = 0.f;
    #pragma unroll
    for (int d = 0; d < 3; d++) {
        float u = uv[d * NF + idx];
        float vb = (float)vBh[d * NF + idx] + (float)vBl[d * NF + idx];
        vout[d * NF + idx] = vb + u * avv;
        dot += u * vv[d * NF + idx];
    }
    float ns = s[idx] + dot * asv + ass;
    s[idx] = ns;
    __bf16 h = (__bf16)ns;
    sh_[idx] = h; sl_[idx] = (__bf16)(ns - (float)h);
}

// ---------------------------------------------------------------- head
__global__ __launch_bounds__(256) void head_kernel(const float* __restrict__ h,
                                                   const float* __restrict__ Wo,
                                                   const float* __restrict__ bo,
                                                   float* __restrict__ out) {
    int n = blockIdx.x * 4 + (threadIdx.x >> 6);
    int lane = threadIdx.x & 63;
    if (n >= NA) return;
    float p = h[(size_t)n * 128 + lane] * Wo[lane] + h[(size_t)n * 128 + 64 + lane] * Wo[64 + lane];
    #pragma unroll
    for (int o = 32; o > 0; o >>= 1) p += __shfl_down(p, o);
    if (lane == 0) out[n] = p + bo[0];
}

// ---------------------------------------------------------------- host
extern "C" void kernel_launch(void* const* d_in, const int* in_sizes, int n_in,
                              void* d_out, int out_size, void* d_ws, size_t ws_size,
                              hipStream_t stream) {
    const float* xyz    = (const float*)d_in[0];
    const int*   z      = (const int*)d_in[1];
    const int*   nbrs   = (const int*)d_in[2];
    const float* embed  = (const float*)d_in[3];
    const float* msg_W1 = (const float*)d_in[4];
    const float* msg_b1 = (const float*)d_in[5];
    const float* msg_W2 = (const float*)d_in[6];
    const float* msg_b2 = (const float*)d_in[7];
    const float* msg_Wd = (const float*)d_in[8];
    const float* msg_bd = (const float*)d_in[9];
    const float* upd_U  = (const float*)d_in[10];
    const float* upd_V  = (const float*)d_in[11];
    const float* upd_Ws1= (const float*)d_in[12];
    const float* upd_bs1= (const float*)d_in[13];
    const float* upd_Ws2= (const float*)d_in[14];
    const float* upd_bs2= (const float*)d_in[15];
    const float* ro_W1  = (const float*)d_in[16];
    const float* ro_b1  = (const float*)d_in[17];
    const float* ro_W2  = (const float*)d_in[18];
    const float* ro_b2  = (const float*)d_in[19];
    const float* fc_W1  = (const float*)d_in[20];
    const float* fc_b1  = (const float*)d_in[21];
    const float* fc_W2  = (const float*)d_in[22];
    const float* fc_b2  = (const float*)d_in[23];
    const float* fc_Wo  = (const float*)d_in[24];
    const float* fc_bo  = (const float*)d_in[25];
    float* out = (float*)d_out;

    char* ws = (char*)d_ws;
    size_t off = 0;
    auto alloc = [&](size_t nbytes) -> char* {
        char* p = ws + off;
        off += (nbytes + 255) / 256 * 256;
        return p;
    };
    // total ~240.5 MB (kept < 256 MiB; R3/R4's 271 MB map is the suspected fault)
    float*  edc   = (float*)alloc((size_t)NE * 24 * 4);
    float*  s     = (float*)alloc((size_t)NA * F * 4);
    __bf16* sh_   = (__bf16*)alloc((size_t)NA * F * 2);
    __bf16* sl_   = (__bf16*)alloc((size_t)NA * F * 2);
    float*  vA    = (float*)alloc((size_t)3 * NF * 4);
    __bf16* vBh   = (__bf16*)alloc((size_t)3 * NF * 2);
    __bf16* vBl   = (__bf16*)alloc((size_t)3 * NF * 2);
    float*  phi   = (float*)alloc((size_t)NA * 384 * 4);   // also readout t3/t4
    __bf16* hid_h = (__bf16*)alloc((size_t)NA * F * 2);
    __bf16* hid_l = (__bf16*)alloc((size_t)NA * F * 2);
    float*  uv    = (float*)alloc((size_t)3 * NF * 4);     // aliased as geometry temp
    float*  vv    = (float*)alloc((size_t)3 * NF * 4);     // aliased as readout t1
    __bf16* stkh  = (__bf16*)alloc((size_t)NA * 256 * 2);  // aliased as readout t2
    __bf16* stkl  = (__bf16*)alloc((size_t)NA * 256 * 2);
    __bf16* wt_h  = (__bf16*)alloc((size_t)3 * 180224 * 2);
    __bf16* wt_l  = (__bf16*)alloc((size_t)3 * 180224 * 2);
    int* act  = (int*)alloc((size_t)NE * 4);
    int* cnt  = (int*)alloc((size_t)NA * 4);
    int* offs = (int*)alloc((size_t)(NA + 1) * 4);
    int* cur  = (int*)alloc((size_t)NA * 4);
    int* jc   = (int*)alloc((size_t)NE * 4);

    float* edata = uv;                 // geometry temp (dead before uv first written)
    float* t1    = vv;                 // readout temps (dead after layers)
    float* t2    = (float*)stkh;
    float* t3    = phi;
    float* t4    = phi + NF;

    // geometry + active-edge CSR
    geom_kernel<<<(NE + 255) / 256, 256, 0, stream>>>(xyz, nbrs, edata, act);
    hipMemsetAsync(cnt, 0, (size_t)NA * 4, stream);
    hist_kernel<<<(NE + 255) / 256, 256, 0, stream>>>(nbrs, act, cnt);
    scan_kernel<<<1, 1024, 0, stream>>>(cnt, offs);
    hipMemsetAsync(cur, 0, (size_t)NA * 4, stream);
    fill_kernel<<<(NE + 255) / 256, 256, 0, stream>>>(nbrs, act, offs, cur, edata, jc, edc);

    // weights + init state
    wconv_kernel<<<(3 * 180224 + 255) / 256, 256, 0, stream>>>(msg_W1, msg_W2, upd_U, upd_V,
                                                               upd_Ws1, upd_Ws2, wt_h, wt_l);
    hipMemsetAsync(vA, 0, (size_t)3 * NF * 4, stream);
    embed_kernel<<<(NA * F + 255) / 256, 256, 0, stream>>>(z, embed, s, sh_, sl_);

    const int GX = (NA + 127) / 128;  // 157
    const int EW = (NA * F + 255) / 256;
    const int WSEG = 180224;
    for (int l = 0; l < 3; l++) {
        const __bf16* w1h = wt_h + (size_t)l * WSEG,          *w1l = wt_l + (size_t)l * WSEG;
        const __bf16* w2h = w1h + 16384,  *w2l = w1l + 16384;
        const __bf16* uh  = w1h + 65536,  *ul  = w1l + 65536;
        const __bf16* vh  = w1h + 81920,  *vl  = w1l + 81920;
        const __bf16* s1h = w1h + 98304,  *s1l = w1l + 98304;
        const __bf16* s2h = w1h + 131072, *s2l = w1l + 131072;

        mgemm_kernel<1, 1><<<dim3(GX, 1), 256, 0, stream>>>(sh_, sl_, w1h, w1l,
            msg_b1 + (size_t)l * 128, 128, 128, nullptr, hid_h, hid_l);
        mgemm_kernel<0, 0><<<dim3(GX, 3), 256, 0, stream>>>(hid_h, hid_l, w2h, w2l,
            msg_b2 + (size_t)l * 384, 128, 384, phi, nullptr, nullptr);
        msg_kernel<<<NA, 128, 0, stream>>>(phi, edc, jc, offs,
            msg_Wd + (size_t)l * 20 * 384, msg_bd + (size_t)l * 384,
            vA, s, vBh, vBl);
        mgemm_uvvv_kernel<<<dim3(GX, 1, 6), 256, 0, stream>>>(vBh, vBl, uh, ul, vh, vl, uv, vv);
        stack_kernel<<<EW, 256, 0, stream>>>(s, vv, stkh, stkl);
        mgemm_kernel<1, 1><<<dim3(GX, 1), 256, 0, stream>>>(stkh, stkl, s1h, s1l,
            upd_bs1 + (size_t)l * 128, 256, 128, nullptr, hid_h, hid_l);
        mgemm_kernel<0, 0><<<dim3(GX, 3), 256, 0, stream>>>(hid_h, hid_l, s2h, s2l,
            upd_bs2 + (size_t)l * 384, 128, 384, phi, nullptr, nullptr);
        update_kernel<<<EW, 256, 0, stream>>>(phi, uv, vv, vBh, vBl, vA, s, sh_, sl_);
    }

    // readout (fp32)
    gemm_kernel<1><<<dim3(GX, 1), 256, 0, stream>>>(s, ro_W1, ro_b1, t1, 128, 64);
    gemm_kernel<0><<<dim3(GX, 1), 256, 0, stream>>>(t1, ro_W2, ro_b2, t2, 64, 64);
    gemm_kernel<2><<<dim3(GX, 2), 256, 0, stream>>>(t2, fc_W1, fc_b1, t3, 64, 128);
    gemm_kernel<2><<<dim3(GX, 2), 256, 0, stream>>>(t3, fc_W2, fc_b2, t4, 128, 128);
    head_kernel<<<NA / 4, 256, 0, stream>>>(t4, fc_Wo, fc_bo, out);
}